// Round 7
// baseline (140.916 us; speedup 1.0000x reference)
//
#include <hip/hip_runtime.h>

#define NUM_BINS 256
#define PLANES 48                     // B*C = 16*3
#define PLANE_ELEMS (512 * 512)       // H*W
#define BPP 64                        // blocks per plane per input -> 6144 blocks
#define THREADS 256                   // 4 waves: waves 0-2 ballot, wave 3 LDS-atomic
#define F4_PER_BLOCK (PLANE_ELEMS / 4 / BPP)   // 1024 float4
#define F4_PER_WAVE (F4_PER_BLOCK / 4)         // 256 float4 (4 per lane)
#define NSUB 16                       // sub-histograms for the atomic wave
#define HSTRIDE 257                   // +1 pad

__global__ __launch_bounds__(THREADS) void hist_kernel(const float* __restrict__ pred,
                                                       const float* __restrict__ target,
                                                       unsigned* __restrict__ hist,
                                                       unsigned* __restrict__ totals) {
    __shared__ alignas(16) unsigned lh[NSUB * HSTRIDE];   // wave 3 private
    const int t = threadIdx.x;
    const int lane = t & 63;
    const int w = t >> 6;

    const int gid   = blockIdx.x;
    const int which = gid / (PLANES * BPP);
    const int rem   = gid - which * (PLANES * BPP);
    const int plane = rem / BPP;
    const int cblk  = rem - plane * BPP;

    const float* src = which ? target : pred;
    const float4* p = reinterpret_cast<const float4*>(src + (size_t)plane * PLANE_ELEMS)
                      + (size_t)cblk * F4_PER_BLOCK;
    unsigned* gh = hist + (size_t)(which * PLANES + plane) * NUM_BINS;
    unsigned long long* gh64 = reinterpret_cast<unsigned long long*>(gh);
    unsigned* tp = &totals[which * PLANES + plane];

    unsigned c0 = 0, c1 = 0, c2 = 0, c3 = 0;   // counts for bins 2L,2L+1,128+2L,128+2L+1

    if (w == 3) {
        // ---------------- LDS-atomic wave (DS pipe) ----------------
        uint4* l4 = reinterpret_cast<uint4*>(lh);
        for (int i = lane; i < (NSUB * HSTRIDE) / 4; i += 64) l4[i] = make_uint4(0, 0, 0, 0);
        asm volatile("s_waitcnt lgkmcnt(0)");   // zeroing done before atomics

        const float4* q = p + 3 * F4_PER_WAVE;
        float4 a0 = q[lane], a1 = q[64 + lane], a2 = q[128 + lane], a3 = q[192 + lane];

        unsigned* sub = lh + (size_t)(lane & (NSUB - 1)) * HSTRIDE;
        float e[16] = {a0.x, a0.y, a0.z, a0.w, a1.x, a1.y, a1.z, a1.w,
                       a2.x, a2.y, a2.z, a2.w, a3.x, a3.y, a3.z, a3.w};
#pragma unroll
        for (int j = 0; j < 16; ++j) {
            int b = (int)(e[j] * 256.0f);       // inputs in [0,1): trunc == floor
            b = b > 255 ? 255 : b;              // 1.0 -> last bin
            atomicAdd(&sub[b], 1u);             // ds_add_u32, no return
        }
        asm volatile("s_waitcnt lgkmcnt(0)");   // atomics done before flush reads

#pragma unroll
        for (int h = 0; h < NSUB; ++h) {
            c0 += lh[h * HSTRIDE + 2 * lane];
            c1 += lh[h * HSTRIDE + 2 * lane + 1];
            c2 += lh[h * HSTRIDE + 128 + 2 * lane];
            c3 += lh[h * HSTRIDE + 129 + 2 * lane];
        }
    } else {
        // ---------------- ballot waves (VALU pipe) ----------------
        // lane L matches elements whose bin bits 1..6 equal L; bits 0,7 select among
        // L's four bins {2L, 2L+1, 128+2L, 128+2L+1}.
        const unsigned m0 = ((lane >> 0) & 1) ? 0u : ~0u;
        const unsigned m1 = ((lane >> 1) & 1) ? 0u : ~0u;
        const unsigned m2 = ((lane >> 2) & 1) ? 0u : ~0u;
        const unsigned m3 = ((lane >> 3) & 1) ? 0u : ~0u;
        const unsigned m4 = ((lane >> 4) & 1) ? 0u : ~0u;
        const unsigned m5 = ((lane >> 5) & 1) ? 0u : ~0u;

        const float4* pw = p + w * F4_PER_WAVE;
        float4 v0 = pw[lane], v1 = pw[64 + lane], v2 = pw[128 + lane], v3 = pw[192 + lane];

#define ROUND(xx)                                                                 \
    do {                                                                          \
        float x = (xx);                                                           \
        int b = (int)(x * 256.0f);                                                \
        b = b > 255 ? 255 : b;                                                    \
        unsigned long long B1 = __ballot(b & 2);                                  \
        unsigned long long B2 = __ballot(b & 4);                                  \
        unsigned long long B3 = __ballot(b & 8);                                  \
        unsigned long long B4 = __ballot(b & 16);                                 \
        unsigned long long B5 = __ballot(b & 32);                                 \
        unsigned long long B6 = __ballot(b & 64);                                 \
        unsigned long long B0 = __ballot(b & 1);                                  \
        unsigned long long B7 = __ballot(b & 128);                                \
        unsigned long long Te0 = ~B0 & ~B7, Te1 = B0 & ~B7;                       \
        unsigned long long Te2 = ~B0 &  B7, Te3 = B0 &  B7;                       \
        unsigned lo = ((unsigned)B1 ^ m0) & ((unsigned)B2 ^ m1) &                 \
                      ((unsigned)B3 ^ m2) & ((unsigned)B4 ^ m3) &                 \
                      ((unsigned)B5 ^ m4) & ((unsigned)B6 ^ m5);                  \
        unsigned hi = ((unsigned)(B1 >> 32) ^ m0) & ((unsigned)(B2 >> 32) ^ m1) & \
                      ((unsigned)(B3 >> 32) ^ m2) & ((unsigned)(B4 >> 32) ^ m3) & \
                      ((unsigned)(B5 >> 32) ^ m4) & ((unsigned)(B6 >> 32) ^ m5);  \
        c0 += __popc(lo & (unsigned)Te0) + __popc(hi & (unsigned)(Te0 >> 32));    \
        c1 += __popc(lo & (unsigned)Te1) + __popc(hi & (unsigned)(Te1 >> 32));    \
        c2 += __popc(lo & (unsigned)Te2) + __popc(hi & (unsigned)(Te2 >> 32));    \
        c3 += __popc(lo & (unsigned)Te3) + __popc(hi & (unsigned)(Te3 >> 32));    \
    } while (0)

        ROUND(v0.x); ROUND(v0.y); ROUND(v0.z); ROUND(v0.w);
        ROUND(v1.x); ROUND(v1.y); ROUND(v1.z); ROUND(v1.w);
        ROUND(v2.x); ROUND(v2.y); ROUND(v2.z); ROUND(v2.w);
        ROUND(v3.x); ROUND(v3.y); ROUND(v3.z); ROUND(v3.w);
#undef ROUND
    }

    // shared flush: 2 packed u64 atomics per lane (bins 2L,2L+1 and 128+2L,129+2L)
    atomicAdd(&gh64[lane],      (unsigned long long)c0 | ((unsigned long long)c1 << 32));
    atomicAdd(&gh64[64 + lane], (unsigned long long)c2 | ((unsigned long long)c3 << 32));

    // plane total from the counts themselves (all inputs are in-range)
    unsigned bt = c0 + c1 + c2 + c3;
    for (int off = 32; off; off >>= 1) bt += __shfl_down(bt, off, 64);
    if (lane == 0) atomicAdd(tp, bt);
}

__global__ __launch_bounds__(1024) void loss_kernel(const unsigned* __restrict__ hist,
                                                    const unsigned* __restrict__ totals,
                                                    float* __restrict__ out) {
    __shared__ double inv[2 * PLANES];
    __shared__ double sd[16];
    const int t = threadIdx.x;
    if (t < 2 * PLANES) inv[t] = 1.0 / ((double)totals[t] + 1e-8);
    __syncthreads();

    const uint4* h4 = reinterpret_cast<const uint4*>(hist);
    double acc = 0.0;
    for (int i = t; i < (PLANES * NUM_BINS) / 4; i += 1024) {
        uint4 hp = h4[i];
        uint4 ht = h4[i + (PLANES * NUM_BINS) / 4];
        const double ip = inv[i >> 6];
        const double it = inv[PLANES + (i >> 6)];
        double d0 = (double)hp.x * ip - (double)ht.x * it;
        double d1 = (double)hp.y * ip - (double)ht.y * it;
        double d2 = (double)hp.z * ip - (double)ht.z * it;
        double d3 = (double)hp.w * ip - (double)ht.w * it;
        acc += d0 * d0 + d1 * d1 + d2 * d2 + d3 * d3;
    }
    for (int off = 32; off; off >>= 1) acc += __shfl_down(acc, off, 64);
    if ((t & 63) == 0) sd[t >> 6] = acc;
    __syncthreads();
    if (t == 0) {
        double s = 0.0;
        for (int w = 0; w < 16; ++w) s += sd[w];
        out[0] = (float)(s / (double)(PLANES * NUM_BINS));
    }
}

extern "C" void kernel_launch(void* const* d_in, const int* in_sizes, int n_in,
                              void* d_out, int out_size, void* d_ws, size_t ws_size,
                              hipStream_t stream) {
    const float* pred   = (const float*)d_in[0];
    const float* target = (const float*)d_in[1];
    float* out = (float*)d_out;
    unsigned* hist   = (unsigned*)d_ws;                          // [2][48][256] u32
    unsigned* totals = hist + (size_t)2 * PLANES * NUM_BINS;     // [96] u32

    hipMemsetAsync(d_ws, 0, ((size_t)2 * PLANES * NUM_BINS + 2 * PLANES) * sizeof(unsigned), stream);
    hist_kernel<<<2 * PLANES * BPP, THREADS, 0, stream>>>(pred, target, hist, totals);
    loss_kernel<<<1, 1024, 0, stream>>>(hist, totals, out);
}

// Round 8
// 61.075 us; speedup vs baseline: 2.3072x; 2.3072x over previous
//
#include <hip/hip_runtime.h>

#define NUM_BINS 256
#define PLANES 48                     // B*C = 16*3
#define PLANE_ELEMS (512 * 512)       // H*W
#define BPP 64                        // blocks per plane per input -> 6144 blocks
#define THREADS 128                   // wave0 = LDS-atomic, wave1 = ballot
#define F4_PER_BLOCK (PLANE_ELEMS / 4 / BPP)   // 1024 float4
#define ATM_F4 7                      // float4 per lane, atomic wave  (448 f4 = 43.75%)
#define BAL_F4 9                      // float4 per lane, ballot wave  (576 f4 = 56.25%)
#define NSUB 8                        // sub-histograms for the atomic wave
#define HSTRIDE 257                   // +1 pad: bank = (row + bin) % 32

__global__ __launch_bounds__(THREADS) void hist_kernel(const float* __restrict__ pred,
                                                       const float* __restrict__ target,
                                                       unsigned* __restrict__ hist,
                                                       unsigned* __restrict__ totals) {
    __shared__ alignas(16) unsigned lh[NSUB * HSTRIDE];   // wave0 private sub-hists
    __shared__ unsigned stage[NUM_BINS];                  // wave1 -> wave0 handoff
    const int t = threadIdx.x;
    const int lane = t & 63;
    const int w = t >> 6;

    const int gid   = blockIdx.x;
    const int which = gid / (PLANES * BPP);
    const int rem   = gid - which * (PLANES * BPP);
    const int plane = rem / BPP;
    const int cblk  = rem - plane * BPP;

    const float* src = which ? target : pred;
    const float4* p = reinterpret_cast<const float4*>(src + (size_t)plane * PLANE_ELEMS)
                      + (size_t)cblk * F4_PER_BLOCK;
    unsigned* gh = hist + (size_t)(which * PLANES + plane) * NUM_BINS;
    unsigned* tp = &totals[which * PLANES + plane];

    // zero sub-hists cooperatively
    uint4* l4 = reinterpret_cast<uint4*>(lh);
    for (int i = t; i < (NSUB * HSTRIDE) / 4; i += THREADS) l4[i] = make_uint4(0, 0, 0, 0);
    __syncthreads();

    unsigned c0 = 0, c1 = 0, c2 = 0, c3 = 0;   // bins {2L, 2L+1, 128+2L, 129+2L}

    if (w == 0) {
        // ---------------- LDS-atomic wave (DS pipe) ----------------
        float4 v[ATM_F4];
#pragma unroll
        for (int i = 0; i < ATM_F4; ++i) v[i] = p[i * 64 + lane];   // 7 loads in flight

        unsigned* sub = lh + (size_t)(lane & (NSUB - 1)) * HSTRIDE;
#pragma unroll
        for (int i = 0; i < ATM_F4; ++i) {
            float e[4] = {v[i].x, v[i].y, v[i].z, v[i].w};
#pragma unroll
            for (int j = 0; j < 4; ++j) {
                int b = (int)(e[j] * 256.0f);    // inputs in [0,1): trunc == floor
                b = b > 255 ? 255 : b;           // 1.0 -> last bin
                atomicAdd(&sub[b], 1u);          // ds_add_u32, no return
            }
        }
        asm volatile("s_waitcnt lgkmcnt(0)" ::: "memory");   // atomics done

#pragma unroll
        for (int h = 0; h < NSUB; ++h) {
            c0 += lh[h * HSTRIDE + 2 * lane];
            c1 += lh[h * HSTRIDE + 2 * lane + 1];
            c2 += lh[h * HSTRIDE + 128 + 2 * lane];
            c3 += lh[h * HSTRIDE + 129 + 2 * lane];
        }
    } else {
        // ---------------- ballot wave (VALU pipe) ----------------
        const unsigned m0 = ((lane >> 0) & 1) ? 0u : ~0u;
        const unsigned m1 = ((lane >> 1) & 1) ? 0u : ~0u;
        const unsigned m2 = ((lane >> 2) & 1) ? 0u : ~0u;
        const unsigned m3 = ((lane >> 3) & 1) ? 0u : ~0u;
        const unsigned m4 = ((lane >> 4) & 1) ? 0u : ~0u;
        const unsigned m5 = ((lane >> 5) & 1) ? 0u : ~0u;

        const float4* q = p + ATM_F4 * 64;
        float4 v[BAL_F4];
#pragma unroll
        for (int i = 0; i < BAL_F4; ++i) v[i] = q[i * 64 + lane];   // 9 loads in flight

#define ROUND(xx)                                                                 \
    do {                                                                          \
        float x = (xx);                                                           \
        int b = (int)(x * 256.0f);                                                \
        b = b > 255 ? 255 : b;                                                    \
        unsigned long long B1 = __ballot(b & 2);                                  \
        unsigned long long B2 = __ballot(b & 4);                                  \
        unsigned long long B3 = __ballot(b & 8);                                  \
        unsigned long long B4 = __ballot(b & 16);                                 \
        unsigned long long B5 = __ballot(b & 32);                                 \
        unsigned long long B6 = __ballot(b & 64);                                 \
        unsigned long long B0 = __ballot(b & 1);                                  \
        unsigned long long B7 = __ballot(b & 128);                                \
        unsigned long long Te0 = ~B0 & ~B7, Te1 = B0 & ~B7;                       \
        unsigned long long Te2 = ~B0 &  B7, Te3 = B0 &  B7;                       \
        unsigned lo = ((unsigned)B1 ^ m0) & ((unsigned)B2 ^ m1) &                 \
                      ((unsigned)B3 ^ m2) & ((unsigned)B4 ^ m3) &                 \
                      ((unsigned)B5 ^ m4) & ((unsigned)B6 ^ m5);                  \
        unsigned hi = ((unsigned)(B1 >> 32) ^ m0) & ((unsigned)(B2 >> 32) ^ m1) & \
                      ((unsigned)(B3 >> 32) ^ m2) & ((unsigned)(B4 >> 32) ^ m3) & \
                      ((unsigned)(B5 >> 32) ^ m4) & ((unsigned)(B6 >> 32) ^ m5);  \
        c0 += __popc(lo & (unsigned)Te0) + __popc(hi & (unsigned)(Te0 >> 32));    \
        c1 += __popc(lo & (unsigned)Te1) + __popc(hi & (unsigned)(Te1 >> 32));    \
        c2 += __popc(lo & (unsigned)Te2) + __popc(hi & (unsigned)(Te2 >> 32));    \
        c3 += __popc(lo & (unsigned)Te3) + __popc(hi & (unsigned)(Te3 >> 32));    \
    } while (0)

#pragma unroll
        for (int i = 0; i < BAL_F4; ++i) {
            ROUND(v[i].x); ROUND(v[i].y); ROUND(v[i].z); ROUND(v[i].w);
        }
#undef ROUND

        // deposit to stage: each lane covers bins {2L,2L+1} and {128+2L,129+2L}
        *reinterpret_cast<unsigned long long*>(&stage[2 * lane]) =
            (unsigned long long)c0 | ((unsigned long long)c1 << 32);
        *reinterpret_cast<unsigned long long*>(&stage[128 + 2 * lane]) =
            (unsigned long long)c2 | ((unsigned long long)c3 << 32);
    }
    __syncthreads();

    if (w == 0) {
        // merge ballot wave's counts, single flush per block
        c0 += stage[2 * lane];
        c1 += stage[2 * lane + 1];
        c2 += stage[128 + 2 * lane];
        c3 += stage[129 + 2 * lane];
        atomicAdd(&gh[2 * lane], c0);
        atomicAdd(&gh[2 * lane + 1], c1);
        atomicAdd(&gh[128 + 2 * lane], c2);
        atomicAdd(&gh[129 + 2 * lane], c3);

        unsigned bt = c0 + c1 + c2 + c3;     // block's element count (all in-range)
        for (int off = 32; off; off >>= 1) bt += __shfl_down(bt, off, 64);
        if (lane == 0) atomicAdd(tp, bt);
    }
}

__global__ __launch_bounds__(1024) void loss_kernel(const unsigned* __restrict__ hist,
                                                    const unsigned* __restrict__ totals,
                                                    float* __restrict__ out) {
    __shared__ double inv[2 * PLANES];
    __shared__ double sd[16];
    const int t = threadIdx.x;
    if (t < 2 * PLANES) inv[t] = 1.0 / ((double)totals[t] + 1e-8);
    __syncthreads();

    const uint4* h4 = reinterpret_cast<const uint4*>(hist);
    double acc = 0.0;
    for (int i = t; i < (PLANES * NUM_BINS) / 4; i += 1024) {
        uint4 hp = h4[i];
        uint4 ht = h4[i + (PLANES * NUM_BINS) / 4];
        const double ip = inv[i >> 6];
        const double it = inv[PLANES + (i >> 6)];
        double d0 = (double)hp.x * ip - (double)ht.x * it;
        double d1 = (double)hp.y * ip - (double)ht.y * it;
        double d2 = (double)hp.z * ip - (double)ht.z * it;
        double d3 = (double)hp.w * ip - (double)ht.w * it;
        acc += d0 * d0 + d1 * d1 + d2 * d2 + d3 * d3;
    }
    for (int off = 32; off; off >>= 1) acc += __shfl_down(acc, off, 64);
    if ((t & 63) == 0) sd[t >> 6] = acc;
    __syncthreads();
    if (t == 0) {
        double s = 0.0;
        for (int w = 0; w < 16; ++w) s += sd[w];
        out[0] = (float)(s / (double)(PLANES * NUM_BINS));
    }
}

extern "C" void kernel_launch(void* const* d_in, const int* in_sizes, int n_in,
                              void* d_out, int out_size, void* d_ws, size_t ws_size,
                              hipStream_t stream) {
    const float* pred   = (const float*)d_in[0];
    const float* target = (const float*)d_in[1];
    float* out = (float*)d_out;
    unsigned* hist   = (unsigned*)d_ws;                          // [2][48][256] u32
    unsigned* totals = hist + (size_t)2 * PLANES * NUM_BINS;     // [96] u32

    hipMemsetAsync(d_ws, 0, ((size_t)2 * PLANES * NUM_BINS + 2 * PLANES) * sizeof(unsigned), stream);
    hist_kernel<<<2 * PLANES * BPP, THREADS, 0, stream>>>(pred, target, hist, totals);
    loss_kernel<<<1, 1024, 0, stream>>>(hist, totals, out);
}

// Round 9
// 30.039 us; speedup vs baseline: 4.6911x; 2.0332x over previous
//
#include <hip/hip_runtime.h>

#define NUM_BINS 256
#define PLANES 48                     // B*C = 16*3
#define PLANE_ELEMS (512 * 512)       // H*W
#define BPP 16                        // blocks per plane per input -> 1536 blocks (6/CU)
#define THREADS 256                   // 4 waves, all LDS-atomic
#define F4_PER_BLOCK (PLANE_ELEMS / 4 / BPP)   // 4096 float4
#define F4_PER_THREAD (F4_PER_BLOCK / THREADS) // 16 -> 64 elems/thread
#define NSUB 8                        // sub-histograms shared by the whole block
#define HSTRIDE 257                   // +1 pad
#define BATCH 4                       // float4 per prefetch batch

__global__ __launch_bounds__(THREADS) void hist_kernel(const float* __restrict__ pred,
                                                       const float* __restrict__ target,
                                                       unsigned* __restrict__ hist,
                                                       unsigned* __restrict__ totals) {
    __shared__ alignas(16) unsigned lh[NSUB * HSTRIDE];
    __shared__ unsigned twave[4];
    const int t = threadIdx.x;
    const int lane = t & 63;

    // zero sub-hists with wide LDS writes (514 uint4 total, 2-3 per thread)
    uint4* l4 = reinterpret_cast<uint4*>(lh);
    for (int i = t; i < (NSUB * HSTRIDE + 3) / 4; i += THREADS) l4[i] = make_uint4(0, 0, 0, 0);
    __syncthreads();

    const int gid   = blockIdx.x;
    const int which = gid / (PLANES * BPP);
    const int rem   = gid - which * (PLANES * BPP);
    const int plane = rem / BPP;
    const int cblk  = rem - plane * BPP;

    const float* src = which ? target : pred;
    const float4* p = reinterpret_cast<const float4*>(src + (size_t)plane * PLANE_ELEMS)
                      + (size_t)cblk * F4_PER_BLOCK;
    unsigned* gh = hist + (size_t)(which * PLANES + plane) * NUM_BINS;
    unsigned* tp = &totals[which * PLANES + plane];

    // each lane uses sub-hist (lane & 7): 8 lanes/sub-hist per wave-op
    unsigned* sub = lh + (size_t)(lane & (NSUB - 1)) * HSTRIDE;

    // double-buffered register prefetch: BATCH float4 in flight while binning
    float4 cur[BATCH], nxt[BATCH];
#pragma unroll
    for (int j = 0; j < BATCH; ++j) cur[j] = p[j * THREADS + t];

    for (int c = 0; c < F4_PER_THREAD / BATCH; ++c) {
        if (c + 1 < F4_PER_THREAD / BATCH) {
#pragma unroll
            for (int j = 0; j < BATCH; ++j)
                nxt[j] = p[(c + 1) * BATCH * THREADS + j * THREADS + t];
        }
#pragma unroll
        for (int j = 0; j < BATCH; ++j) {
            float e[4] = {cur[j].x, cur[j].y, cur[j].z, cur[j].w};
#pragma unroll
            for (int k = 0; k < 4; ++k) {
                int b = (int)(e[k] * 256.0f);   // inputs in [0,1]: trunc == floor
                b = b > 255 ? 255 : b;          // 1.0 -> last bin
                atomicAdd(&sub[b], 1u);         // ds_add_u32, no return
            }
        }
#pragma unroll
        for (int j = 0; j < BATCH; ++j) cur[j] = nxt[j];
    }
    __syncthreads();

    // flush: thread t owns bin t — 8 LDS reads + 1 global atomic
    unsigned c = 0;
#pragma unroll
    for (int h = 0; h < NSUB; ++h) c += lh[h * HSTRIDE + t];
    if (c) atomicAdd(&gh[t], c);

    // block total -> plane total
    unsigned bt = c;
    for (int off = 32; off; off >>= 1) bt += __shfl_down(bt, off, 64);
    if ((t & 63) == 0) twave[t >> 6] = bt;
    __syncthreads();
    if (t == 0) atomicAdd(tp, twave[0] + twave[1] + twave[2] + twave[3]);
}

__global__ __launch_bounds__(1024) void loss_kernel(const unsigned* __restrict__ hist,
                                                    const unsigned* __restrict__ totals,
                                                    float* __restrict__ out) {
    __shared__ double inv[2 * PLANES];
    __shared__ double sd[16];
    const int t = threadIdx.x;
    if (t < 2 * PLANES) inv[t] = 1.0 / ((double)totals[t] + 1e-8);
    __syncthreads();

    const uint4* h4 = reinterpret_cast<const uint4*>(hist);
    double acc = 0.0;
    for (int i = t; i < (PLANES * NUM_BINS) / 4; i += 1024) {
        uint4 hp = h4[i];
        uint4 ht = h4[i + (PLANES * NUM_BINS) / 4];
        const double ip = inv[i >> 6];
        const double it = inv[PLANES + (i >> 6)];
        double d0 = (double)hp.x * ip - (double)ht.x * it;
        double d1 = (double)hp.y * ip - (double)ht.y * it;
        double d2 = (double)hp.z * ip - (double)ht.z * it;
        double d3 = (double)hp.w * ip - (double)ht.w * it;
        acc += d0 * d0 + d1 * d1 + d2 * d2 + d3 * d3;
    }
    for (int off = 32; off; off >>= 1) acc += __shfl_down(acc, off, 64);
    if ((t & 63) == 0) sd[t >> 6] = acc;
    __syncthreads();
    if (t == 0) {
        double s = 0.0;
        for (int w = 0; w < 16; ++w) s += sd[w];
        out[0] = (float)(s / (double)(PLANES * NUM_BINS));
    }
}

extern "C" void kernel_launch(void* const* d_in, const int* in_sizes, int n_in,
                              void* d_out, int out_size, void* d_ws, size_t ws_size,
                              hipStream_t stream) {
    const float* pred   = (const float*)d_in[0];
    const float* target = (const float*)d_in[1];
    float* out = (float*)d_out;
    unsigned* hist   = (unsigned*)d_ws;                          // [2][48][256] u32
    unsigned* totals = hist + (size_t)2 * PLANES * NUM_BINS;     // [96] u32

    hipMemsetAsync(d_ws, 0, ((size_t)2 * PLANES * NUM_BINS + 2 * PLANES) * sizeof(unsigned), stream);
    hist_kernel<<<2 * PLANES * BPP, THREADS, 0, stream>>>(pred, target, hist, totals);
    loss_kernel<<<1, 1024, 0, stream>>>(hist, totals, out);
}

// Round 10
// 24.926 us; speedup vs baseline: 5.6533x; 1.2051x over previous
//
#include <hip/hip_runtime.h>

#define NUM_BINS 256
#define PLANES 48                     // B*C = 16*3
#define PLANE_ELEMS (512 * 512)       // H*W
#define BPP 16                        // blocks per plane per input -> 1536 blocks (6/CU)
#define THREADS 256                   // 4 waves, all LDS-atomic
#define F4_PER_BLOCK (PLANE_ELEMS / 4 / BPP)   // 4096 float4
#define F4_PER_THREAD (F4_PER_BLOCK / THREADS) // 16 -> 64 elems/thread
#define NSUB 8                        // sub-histograms shared by the whole block
#define HSTRIDE 257                   // +1 pad
#define BATCH 4                       // float4 per prefetch batch

__global__ __launch_bounds__(THREADS) void hist_kernel(const float* __restrict__ pred,
                                                       const float* __restrict__ target,
                                                       unsigned* __restrict__ part) {
    __shared__ alignas(16) unsigned lh[NSUB * HSTRIDE];
    const int t = threadIdx.x;
    const int lane = t & 63;

    // zero sub-hists with wide LDS writes
    uint4* l4 = reinterpret_cast<uint4*>(lh);
    for (int i = t; i < (NSUB * HSTRIDE + 3) / 4; i += THREADS) l4[i] = make_uint4(0, 0, 0, 0);
    __syncthreads();

    const int gid   = blockIdx.x;
    const int which = gid / (PLANES * BPP);
    const int rem   = gid - which * (PLANES * BPP);
    const int plane = rem / BPP;
    const int cblk  = rem - plane * BPP;

    const float* src = which ? target : pred;
    const float4* p = reinterpret_cast<const float4*>(src + (size_t)plane * PLANE_ELEMS)
                      + (size_t)cblk * F4_PER_BLOCK;

    // each lane uses sub-hist (lane & 7): 8 lanes/sub-hist per wave-op
    unsigned* sub = lh + (size_t)(lane & (NSUB - 1)) * HSTRIDE;

    // double-buffered register prefetch: BATCH float4 in flight while binning
    float4 cur[BATCH], nxt[BATCH];
#pragma unroll
    for (int j = 0; j < BATCH; ++j) cur[j] = p[j * THREADS + t];

    for (int c = 0; c < F4_PER_THREAD / BATCH; ++c) {
        if (c + 1 < F4_PER_THREAD / BATCH) {
#pragma unroll
            for (int j = 0; j < BATCH; ++j)
                nxt[j] = p[(c + 1) * BATCH * THREADS + j * THREADS + t];
        }
#pragma unroll
        for (int j = 0; j < BATCH; ++j) {
            float e[4] = {cur[j].x, cur[j].y, cur[j].z, cur[j].w};
#pragma unroll
            for (int k = 0; k < 4; ++k) {
                int b = (int)(e[k] * 256.0f);   // inputs in [0,1]: trunc == floor
                b = b > 255 ? 255 : b;          // 1.0 -> last bin
                atomicAdd(&sub[b], 1u);         // ds_add_u32, no return
            }
        }
#pragma unroll
        for (int j = 0; j < BATCH; ++j) cur[j] = nxt[j];
    }
    __syncthreads();

    // flush: thread t owns bin t — 8 LDS reads + ONE coalesced plain store
    unsigned c = 0;
#pragma unroll
    for (int h = 0; h < NSUB; ++h) c += lh[h * HSTRIDE + t];
    part[(size_t)gid * NUM_BINS + t] = c;       // every slot overwritten every call
}

// one block per plane: merge 16+16 partials, normalize, per-plane sum of d^2
__global__ __launch_bounds__(THREADS) void plane_kernel(const unsigned* __restrict__ part,
                                                        double* __restrict__ plane_loss) {
    __shared__ unsigned wa[4], wb[4];
    __shared__ double sd[THREADS];
    const int t = threadIdx.x;
    const int p = blockIdx.x;

    const unsigned* bp = part + (size_t)p * BPP * NUM_BINS;                   // pred partials
    const unsigned* bt = part + (size_t)(PLANES + p) * BPP * NUM_BINS;        // target partials
    unsigned hp = 0, ht = 0;
#pragma unroll
    for (int j = 0; j < BPP; ++j) {
        hp += bp[j * NUM_BINS + t];
        ht += bt[j * NUM_BINS + t];
    }

    // plane totals (exact integer counts)
    unsigned a = hp, b = ht;
    for (int off = 32; off; off >>= 1) {
        a += __shfl_down(a, off, 64);
        b += __shfl_down(b, off, 64);
    }
    if ((t & 63) == 0) { wa[t >> 6] = a; wb[t >> 6] = b; }
    __syncthreads();
    const unsigned Sp = wa[0] + wa[1] + wa[2] + wa[3];
    const unsigned St = wb[0] + wb[1] + wb[2] + wb[3];

    const double ip = 1.0 / ((double)Sp + 1e-8);
    const double it = 1.0 / ((double)St + 1e-8);
    const double d = (double)hp * ip - (double)ht * it;
    sd[t] = d * d;
    __syncthreads();
    for (int off = THREADS / 2; off; off >>= 1) {   // fixed-order tree: deterministic
        if (t < off) sd[t] += sd[t + off];
        __syncthreads();
    }
    if (t == 0) plane_loss[p] = sd[0];
}

__global__ __launch_bounds__(64) void final_kernel(const double* __restrict__ plane_loss,
                                                   float* __restrict__ out) {
    const int t = threadIdx.x;
    double v = (t < PLANES) ? plane_loss[t] : 0.0;
    for (int off = 32; off; off >>= 1) v += __shfl_down(v, off, 64);
    if (t == 0) out[0] = (float)(v / (double)(PLANES * NUM_BINS));
}

extern "C" void kernel_launch(void* const* d_in, const int* in_sizes, int n_in,
                              void* d_out, int out_size, void* d_ws, size_t ws_size,
                              hipStream_t stream) {
    const float* pred   = (const float*)d_in[0];
    const float* target = (const float*)d_in[1];
    float* out = (float*)d_out;
    unsigned* part = (unsigned*)d_ws;                              // [2*48*16][256] u32 = 1.57 MB
    double* plane_loss = reinterpret_cast<double*>(
        (char*)d_ws + (size_t)2 * PLANES * BPP * NUM_BINS * sizeof(unsigned));  // [48] f64, 8B-aligned

    hist_kernel<<<2 * PLANES * BPP, THREADS, 0, stream>>>(pred, target, part);
    plane_kernel<<<PLANES, THREADS, 0, stream>>>(part, plane_loss);
    final_kernel<<<1, 64, 0, stream>>>(plane_loss, out);
}